// Round 17
// baseline (378.045 us; speedup 1.0000x reference)
//
#include <hip/hip_runtime.h>

#define NN 4096
#define DD 64
#define NBLK 256      // merged roles: block b owns f-rows and g-rows [16b, 16b+16)
#define NTHR 1024
#define NWAVE 16
#define ITERS 50

typedef __attribute__((ext_vector_type(8))) short short8;
typedef __attribute__((ext_vector_type(4))) float f32x4;

#define C2f     0.4808983469629878f   /* 1/(eps*ln2), eps=3 */
#define EPSLN2f 2.0794415416798359f   /* eps*ln2 */
#define TWELVEf 12.0f                 /* log2(4096) marginal term */

#define LLC_LDU(p)    __hip_atomic_load((p), __ATOMIC_RELAXED, __HIP_MEMORY_SCOPE_AGENT)
#define LLC_STU(p, v) __hip_atomic_store((p), (v), __ATOMIC_RELAXED, __HIP_MEMORY_SCOPE_AGENT)

__device__ inline short bf16_of(float f) {
  unsigned u = __float_as_uint(f);
  u += 0x7fffu + ((u >> 16) & 1u);   // RTNE, inputs finite
  return (short)(u >> 16);
}
// pack two positive floats as bf16 pair (RTNE)
__device__ inline unsigned pack_bf16(float e0, float e1) {
  return ((unsigned)(unsigned short)bf16_of(e1) << 16) |
         (unsigned)(unsigned short)bf16_of(e0);
}

__device__ inline void pollbar(unsigned* bar, unsigned target) {
  while (__hip_atomic_load(bar, __ATOMIC_RELAXED, __HIP_MEMORY_SCOPE_AGENT) < target)
    __builtin_amdgcn_s_sleep(2);
}
__device__ inline void arrive(unsigned* cnt, int grp, unsigned* bar, unsigned phase) {
  unsigned old = atomicAdd(&cnt[grp << 5], 1u);
  if (old == (phase << 5) - 1u) atomicAdd(bar, 1u);
}

// publish-index -> tag in {1,2,3}; 0 (memset state) never matches; a slot at index h
// is only overwritten (h+2) after all consumers passed the h+1 all-to-all.
__device__ inline unsigned tag_of(int h) { return (unsigned)(h % 3) + 1u; }

// Fused poll+stage, parallel retry, NO sleep backoff (poll period = load RTT,
// lower detect latency AND variance). Published value IS w = exp2(bias) — the
// consumer does no trans work at all. Tag bits = ~3ulp noise on w, negligible.
__device__ __forceinline__ void poll_stage(unsigned* __restrict__ src, unsigned tagIn,
                                           float* w_lds, int tid) {
  unsigned v[4];
#pragma unroll
  for (int q = 0; q < 4; ++q) v[q] = LLC_LDU(src + tid + (q << 10));
  for (;;) {
    unsigned miss = 0;
#pragma unroll
    for (int q = 0; q < 4; ++q) miss |= ((v[q] & 3u) != tagIn) ? (1u << q) : 0u;
    if (!miss) break;
#pragma unroll
    for (int q = 0; q < 4; ++q)
      if (miss & (1u << q)) v[q] = LLC_LDU(src + tid + (q << 10));
  }
#pragma unroll
  for (int q = 0; q < 4; ++q)
    w_lds[tid + (q << 10)] = __uint_as_float(v[q]);
}

__global__ __launch_bounds__(NTHR, 4)   // 1 block/CU (148 KB LDS also enforces this)
void sink_kernel(const float* __restrict__ X,
                 const float* __restrict__ Y,
                 float* __restrict__ out,
                 unsigned char* __restrict__ ws) {
  unsigned* barI = (unsigned*)ws;             // one-time init barrier
  unsigned* cntI = (unsigned*)(ws + 512);     // 8 groups x 128B
  unsigned* bGt  = (unsigned*)(ws + 8192);    // tagged w_g = exp2(g-bias)
  unsigned* bFt  = (unsigned*)(ws + 24576);   // tagged w_f = exp2(f-bias)
  short* Xb = (short*)(ws + 65536);           // 4096x64 bf16
  short* Yb = Xb + NN * DD;

  const int tid  = threadIdx.x;
  const int blk  = blockIdx.x;
  const int wave = tid >> 6;
  const int lane = tid & 63;
  const int i0   = blk << 4;
  const int c0   = (wave << 4) + (lane & 15); // this thread's column slot (mod 256)

  __shared__ uint4 sgl4[8][NTHR];             // E_g: 16 tiles pair-packed bf16 (128 KB)
  __shared__ float w_lds[NN];                 // staged w (16 KB)
  __shared__ float red[16];                   // row accumulators
  __shared__ float sh_xsq[16], sh_ysq[16];

  // ---- init: convert own 16 rows of BOTH matrices + row norms ----
  Xb[blk * NTHR + tid] = bf16_of(X[blk * NTHR + tid]);
  Yb[blk * NTHR + tid] = bf16_of(Y[blk * NTHR + tid]);
  if (tid < 16) red[tid] = 0.f;
  {
    const int row = i0 + wave;
    float vx = X[row * DD + lane];
    float vy = Y[row * DD + lane];
    float sx = vx * vx, sy = vy * vy;
#pragma unroll
    for (int o = 1; o < 64; o <<= 1) { sx += __shfl_xor(sx, o); sy += __shfl_xor(sy, o); }
    if (lane == 0) { sh_xsq[wave] = 0.5f * sx; sh_ysq[wave] = 0.5f * sy; }
  }
  __syncthreads();
  if (tid == 0) {                             // one-time fenced barrier for Xb/Yb
    __threadfence();
    arrive(cntI, blk >> 5, barI, 1);
    pollbar(barI, 8u);
  }
  __syncthreads();

  // initial g publish (g0=0): w = exp2(-ysq*c), publish index h=0 -> tag 1
  if (tid < 16) {
    const float w0 = __builtin_amdgcn_exp2f(-sh_ysq[tid] * C2f);
    LLC_STU(bGt + i0 + tid, (__float_as_uint(w0) & ~3u) | 1u);
  }

  // ---- build E_f (regs) and E_g (LDS, pair-packed): E = exp2(dot*c), bf16.
  //      exp2 args bounded (|dot*c| <= ~22) -> E in 2^±22, bf16-safe. ----
  uint2 sf[16];
  {
    const short* ap = Xb + ((i0 + (lane & 15)) << 6) + ((lane >> 4) << 3);
    short8 a0 = *(const short8*)ap;
    short8 a1 = *(const short8*)(ap + 32);
#pragma unroll
    for (int k = 0; k < 16; ++k) {
      const int jb = (wave << 4) + (k << 8);
      const short* bp = Yb + ((jb + (lane & 15)) << 6) + ((lane >> 4) << 3);
      short8 b0 = *(const short8*)bp;
      short8 b1 = *(const short8*)(bp + 32);
      f32x4 acc = {0.f, 0.f, 0.f, 0.f};
      acc = __builtin_amdgcn_mfma_f32_16x16x32_bf16(a0, b0, acc, 0, 0, 0);
      acc = __builtin_amdgcn_mfma_f32_16x16x32_bf16(a1, b1, acc, 0, 0, 0);
      sf[k].x = pack_bf16(__builtin_amdgcn_exp2f(acc[0] * C2f),
                          __builtin_amdgcn_exp2f(acc[1] * C2f));
      sf[k].y = pack_bf16(__builtin_amdgcn_exp2f(acc[2] * C2f),
                          __builtin_amdgcn_exp2f(acc[3] * C2f));
    }
  }
  {
    const short* ap = Yb + ((i0 + (lane & 15)) << 6) + ((lane >> 4) << 3);
    short8 a0 = *(const short8*)ap;
    short8 a1 = *(const short8*)(ap + 32);
#pragma unroll
    for (int kk = 0; kk < 8; ++kk) {
      unsigned wp[4];
#pragma unroll
      for (int h = 0; h < 2; ++h) {
        const int k = 2 * kk + h;
        const int jb = (wave << 4) + (k << 8);
        const short* bp = Xb + ((jb + (lane & 15)) << 6) + ((lane >> 4) << 3);
        short8 b0 = *(const short8*)bp;
        short8 b1 = *(const short8*)(bp + 32);
        f32x4 acc = {0.f, 0.f, 0.f, 0.f};
        acc = __builtin_amdgcn_mfma_f32_16x16x32_bf16(a0, b0, acc, 0, 0, 0);
        acc = __builtin_amdgcn_mfma_f32_16x16x32_bf16(a1, b1, acc, 0, 0, 0);
        wp[2 * h]     = pack_bf16(__builtin_amdgcn_exp2f(acc[0] * C2f),
                                  __builtin_amdgcn_exp2f(acc[1] * C2f));
        wp[2 * h + 1] = pack_bf16(__builtin_amdgcn_exp2f(acc[2] * C2f),
                                  __builtin_amdgcn_exp2f(acc[3] * C2f));
      }
      sgl4[kk][tid] = make_uint4(wp[0], wp[1], wp[2], wp[3]);
    }
  }

  // publish indices: bGt gets h=0 (init) and h=2it+2 (g_it); bFt gets h=2it+1 (f_it).
  // f at it consumes bGt h=2it; g at it consumes bFt h=2it+1.
  // Published value: w = exp2((pot-sq)*c) = 2^12 / Sigma  (one v_rcp + mul).
  for (int it = 0; it < ITERS; ++it) {
    const bool last = (it == ITERS - 1);

    // ================= f half-step (E_f in registers) =================
    {
      const unsigned tagIn  = tag_of(2 * it);
      const unsigned tagOut = tag_of(2 * it + 1);
      poll_stage(bGt, tagIn, w_lds, tid);
      __syncthreads();
      float sum[4] = {0.f, 0.f, 0.f, 0.f};
#pragma unroll
      for (int k = 0; k < 16; ++k) {
        const float w = w_lds[c0 + (k << 8)];       // 4-way broadcast, conflict-free
        const unsigned p0 = sf[k].x, p1 = sf[k].y;
        sum[0] = __builtin_fmaf(__uint_as_float(p0 << 16),          w, sum[0]);
        sum[1] = __builtin_fmaf(__uint_as_float(p0 & 0xffff0000u),  w, sum[1]);
        sum[2] = __builtin_fmaf(__uint_as_float(p1 << 16),          w, sum[2]);
        sum[3] = __builtin_fmaf(__uint_as_float(p1 & 0xffff0000u),  w, sum[3]);
      }
#pragma unroll
      for (int o = 1; o <= 8; o <<= 1)
#pragma unroll
        for (int r = 0; r < 4; ++r) sum[r] += __shfl_xor(sum[r], o);
      if ((lane & 15) == 0)
#pragma unroll
        for (int r = 0; r < 4; ++r) atomicAdd(&red[((lane >> 4) << 2) + r], sum[r]);
      __syncthreads();
      if (tid < 16) {
        const float t = red[tid];
        const float wOut = 4096.0f * __frcp_rn(t);           // 2^12 / Sigma
        LLC_STU(bFt + i0 + tid, (__float_as_uint(wOut) & ~3u) | tagOut);
        red[tid] = 0.f;                                      // re-arm for g half
        if (last) {
          const float bc = TWELVEf - __builtin_amdgcn_logf(t);   // v_log_f32 = log2
          out[i0 + tid] = sh_xsq[tid] + EPSLN2f * bc;
        }
      }
      // no extra sync: g's stage-sync is gated on tid<16 arriving after the zero
    }

    // ================= g half-step (E_g in LDS) =================
    {
      const unsigned tagIn  = tag_of(2 * it + 1);
      const unsigned tagOut = tag_of(2 * it + 2);
      poll_stage(bFt, tagIn, w_lds, tid);
      __syncthreads();
      float sum[4] = {0.f, 0.f, 0.f, 0.f};
#pragma unroll
      for (int kk = 0; kk < 8; ++kk) {
        const uint4 e = sgl4[kk][tid];                 // ds_read_b128, conflict-free
        const float w0 = w_lds[c0 + ((2 * kk) << 8)];
        const float w1 = w_lds[c0 + ((2 * kk + 1) << 8)];
        sum[0] = __builtin_fmaf(__uint_as_float(e.x << 16),         w0, sum[0]);
        sum[1] = __builtin_fmaf(__uint_as_float(e.x & 0xffff0000u), w0, sum[1]);
        sum[2] = __builtin_fmaf(__uint_as_float(e.y << 16),         w0, sum[2]);
        sum[3] = __builtin_fmaf(__uint_as_float(e.y & 0xffff0000u), w0, sum[3]);
        sum[0] = __builtin_fmaf(__uint_as_float(e.z << 16),         w1, sum[0]);
        sum[1] = __builtin_fmaf(__uint_as_float(e.z & 0xffff0000u), w1, sum[1]);
        sum[2] = __builtin_fmaf(__uint_as_float(e.w << 16),         w1, sum[2]);
        sum[3] = __builtin_fmaf(__uint_as_float(e.w & 0xffff0000u), w1, sum[3]);
      }
#pragma unroll
      for (int o = 1; o <= 8; o <<= 1)
#pragma unroll
        for (int r = 0; r < 4; ++r) sum[r] += __shfl_xor(sum[r], o);
      if ((lane & 15) == 0)
#pragma unroll
        for (int r = 0; r < 4; ++r) atomicAdd(&red[((lane >> 4) << 2) + r], sum[r]);
      __syncthreads();
      if (tid < 16) {
        const float t = red[tid];
        const float wOut = 4096.0f * __frcp_rn(t);
        LLC_STU(bGt + i0 + tid, (__float_as_uint(wOut) & ~3u) | tagOut);
        red[tid] = 0.f;                                      // re-arm for next f half
        if (last) {
          const float bc = TWELVEf - __builtin_amdgcn_logf(t);
          out[NN + i0 + tid] = sh_ysq[tid] + EPSLN2f * bc;
        }
      }
      // next f stage-sync gates on tid<16 as above
    }
  }
}

extern "C" void kernel_launch(void* const* d_in, const int* in_sizes, int n_in,
                              void* d_out, int out_size, void* d_ws, size_t ws_size,
                              hipStream_t stream) {
  const float* X = (const float*)d_in[0];
  const float* Y = (const float*)d_in[1];
  float* out = (float*)d_out;
  unsigned char* ws = (unsigned char*)d_ws;
  // zero init-barrier counters + both tagged-w arrays (tag 0 = never-ready)
  hipMemsetAsync(d_ws, 0, 65536, stream);
  sink_kernel<<<dim3(NBLK), dim3(NTHR), 0, stream>>>(X, Y, out, ws);
}